// Round 2
// baseline (1329.843 us; speedup 1.0000x reference)
//
#include <hip/hip_runtime.h>
#include <cstdint>

#define NXI  2048
#define LLEN 2048
#define NN   1024
#define MM   1024
#define SS   6144
#define EPSV 0.001f
#define NCHEB 28

typedef __attribute__((ext_vector_type(8))) __bf16 bf16x8;
typedef __attribute__((ext_vector_type(4))) float  f32x4;
typedef __attribute__((ext_vector_type(8))) unsigned short us8;
typedef unsigned short ushort_t;

// ---------- helpers ----------
__device__ __forceinline__ unsigned short f2bf(float f) {
  unsigned u = __float_as_uint(f);
  unsigned r = (u + 0x7FFFu + ((u >> 16) & 1u)) >> 16;   // RNE
  return (unsigned short)r;
}

__device__ __forceinline__ void gld16(const void* g, void* l) {
  __builtin_amdgcn_global_load_lds((const __attribute__((address_space(1))) void*)g,
                                   (__attribute__((address_space(3))) void*)l,
                                   16, 0, 0);
}

// ---------- 1) transpose + f32->bf16: XT[i][k] = bf16(X[k][i]) ----------
__global__ __launch_bounds__(256) void k_transpose(const float* __restrict__ X,
                                                   ushort_t* __restrict__ XT) {
  __shared__ float tile[64][65];
  const int bx = blockIdx.x, by = blockIdx.y;
  const int t = threadIdx.x;
  const int r = t >> 2, c0 = (t & 3) << 4;
  const float* src = X + (size_t)(by * 64 + r) * SS + bx * 64 + c0;
#pragma unroll
  for (int s = 0; s < 16; s += 4) {
    const float4 v = *(const float4*)(src + s);
    tile[r][c0 + s]     = v.x;
    tile[r][c0 + s + 1] = v.y;
    tile[r][c0 + s + 2] = v.z;
    tile[r][c0 + s + 3] = v.w;
  }
  __syncthreads();
  ushort_t* dst = XT + (size_t)(bx * 64 + r) * SS + by * 64 + c0;
  us8 o0, o1;
#pragma unroll
  for (int s = 0; s < 8; ++s) o0[s] = f2bf(tile[c0 + s][r]);
#pragma unroll
  for (int s = 0; s < 8; ++s) o1[s] = f2bf(tile[c0 + 8 + s][r]);
  *(us8*)dst = o0;
  *(us8*)(dst + 8) = o1;
}

// ---------- 2) H blocks: H[z] = XT[Rblk rows] * XT[Cblk rows]^T (+EPS on diag) ----------
// z: 0=(0,0)H11 1=(1,0)H21 2=(1,1)H22 3=(2,0)H31 4=(2,1)H32 5=(2,2)H33
__global__ __launch_bounds__(256) void k_syrk(const ushort_t* __restrict__ XT,
                                              float* __restrict__ Hws) {
  const int z = blockIdx.z;
  const int Rb = (z >= 3) ? 2 : ((z >= 1) ? 1 : 0);
  const int Cb = z - (Rb * (Rb + 1)) / 2;
  const int bm = blockIdx.y, bn = blockIdx.x;
  if (z == 2 && bn > bm) return;   // H22: only lower tiles needed (strict-lower + diag)
  float* __restrict__ Hout = Hws + (size_t)z * (2048ull * 2048ull);

  const int t = threadIdx.x;
  const int lane = t & 63, wave = t >> 6;
  const int wm = wave >> 1, wn = wave & 1;

  __shared__ ushort_t As[4096];
  __shared__ ushort_t Bs[4096];

  const int c0 = t, c1 = t + 256;
  const size_t arow0 = (size_t)Rb * 2048 + (size_t)bm * 128;
  const size_t brow0 = (size_t)Cb * 2048 + (size_t)bn * 128;
  const ushort_t* pa0 = XT + (arow0 + (size_t)(c0 >> 2)) * SS + (c0 & 3) * 8;
  const ushort_t* pa1 = XT + (arow0 + (size_t)(c1 >> 2)) * SS + (c1 & 3) * 8;
  const ushort_t* pb0 = XT + (brow0 + (size_t)(c0 >> 2)) * SS + (c0 & 3) * 8;
  const ushort_t* pb1 = XT + (brow0 + (size_t)(c1 >> 2)) * SS + (c1 & 3) * 8;

  f32x4 acc[4][4] = {};
  const int krow = (lane >> 4) * 8;
  const int rl = lane & 15;

  for (int k0 = 0; k0 < SS; k0 += 32) {
    __syncthreads();
    gld16(pa0 + k0, &As[c0 * 8]);
    gld16(pa1 + k0, &As[c1 * 8]);
    gld16(pb0 + k0, &Bs[c0 * 8]);
    gld16(pb1 + k0, &Bs[c1 * 8]);
    __syncthreads();
    bf16x8 af[4], bfr[4];
#pragma unroll
    for (int m = 0; m < 4; ++m)
      af[m] = *(const bf16x8*)&As[(wm * 64 + m * 16 + rl) * 32 + krow];
#pragma unroll
    for (int n = 0; n < 4; ++n)
      bfr[n] = *(const bf16x8*)&Bs[(wn * 64 + n * 16 + rl) * 32 + krow];
#pragma unroll
    for (int m = 0; m < 4; ++m)
#pragma unroll
      for (int n = 0; n < 4; ++n)
        acc[m][n] = __builtin_amdgcn_mfma_f32_16x16x32_bf16(af[m], bfr[n], acc[m][n], 0, 0, 0);
  }

  const int cr = (lane >> 4) << 2, cc = lane & 15;
  const bool dg = (Rb == Cb);
#pragma unroll
  for (int m = 0; m < 4; ++m) {
#pragma unroll
    for (int n = 0; n < 4; ++n) {
#pragma unroll
      for (int v = 0; v < 4; ++v) {
        const int row = bm * 128 + wm * 64 + m * 16 + cr + v;
        const int col = bn * 128 + wn * 64 + n * 16 + cc;
        float val = acc[m][n][v];
        if (dg && row == col) val += EPSV;
        Hout[(size_t)row * 2048 + col] = val;
      }
    }
  }
}

// ---------- 3) E = 0.5*(H11 + H33 + Y - Y^T), in-place into H11 ----------
__global__ __launch_bounds__(256) void k_combine(float* __restrict__ H0,
                                                 const float* __restrict__ H5,
                                                 const float* __restrict__ Y) {
  __shared__ float yt[64][65];
  const int bx = blockIdx.x, by = blockIdx.y;
  const int t = threadIdx.x;
  const int r = t >> 2, c0 = (t & 3) << 4;
  const float* ys = Y + (size_t)(bx * 64 + r) * 2048 + by * 64 + c0;
#pragma unroll
  for (int s = 0; s < 16; s += 4) {
    const float4 v = *(const float4*)(ys + s);
    yt[r][c0 + s]     = v.x;
    yt[r][c0 + s + 1] = v.y;
    yt[r][c0 + s + 2] = v.z;
    yt[r][c0 + s + 3] = v.w;
  }
  __syncthreads();
  const size_t base = (size_t)(by * 64 + r) * 2048 + bx * 64 + c0;
#pragma unroll
  for (int s = 0; s < 16; s += 4) {
    const float4 a = *(const float4*)(H0 + base + s);
    const float4 b = *(const float4*)(H5 + base + s);
    const float4 y = *(const float4*)(Y + base + s);
    float4 e;
    e.x = 0.5f * (a.x + b.x + y.x - yt[c0 + s][r]);
    e.y = 0.5f * (a.y + b.y + y.y - yt[c0 + s + 1][r]);
    e.z = 0.5f * (a.z + b.z + y.z - yt[c0 + s + 2][r]);
    e.w = 0.5f * (a.w + b.w + y.w - yt[c0 + s + 3][r]);
    *(float4*)(H0 + base + s) = e;
  }
}

// ---------- 4) invLam[i] = 1/(0.5*H22[i][i]) ----------
__global__ __launch_bounds__(256) void k_lam(const float* __restrict__ H22,
                                             float* __restrict__ invLam) {
  const int i = blockIdx.x * 256 + threadIdx.x;
  if (i < NXI) invLam[i] = 2.0f / H22[(size_t)i * 2048 + i];
}

// ---------- 5) base[i] = -(H21@xi)[i] + (D12@w)[i] ----------
__global__ __launch_bounds__(256) void k_base(const float* __restrict__ H21,
                                              const float* __restrict__ D12,
                                              const float* __restrict__ xi,
                                              const float* __restrict__ w,
                                              float* __restrict__ bacc) {
  const int t = threadIdx.x;
  const int lane = t & 63;
  const int wv = blockIdx.x * 4 + (t >> 6);
  for (int row = wv; row < LLEN; row += 128) {
    const float* hr = H21 + (size_t)row * NXI;
    float s = 0.f;
    for (int k0 = 0; k0 < NXI; k0 += 256) {
      const int li = k0 + lane * 4;
      const float4 h = *(const float4*)(hr + li);
      const float4 x4 = *(const float4*)(xi + li);
      s += h.x * x4.x + h.y * x4.y + h.z * x4.z + h.w * x4.w;
    }
    const float* dr = D12 + (size_t)row * NN;
    float s2 = 0.f;
    for (int k0 = 0; k0 < NN; k0 += 256) {
      const int li = k0 + lane * 4;
      const float4 h = *(const float4*)(dr + li);
      const float4 x4 = *(const float4*)(w + li);
      s2 += h.x * x4.x + h.y * x4.y + h.z * x4.z + h.w * x4.w;
    }
    float tot = s2 - s;
#pragma unroll
    for (int off = 32; off > 0; off >>= 1) tot += __shfl_xor(tot, off, 64);
    if (lane == 0) bacc[row] = tot;
  }
}

// ---------- 6) sequential eps solve: producer/consumer spin kernel ----------
// flags[0] = pub (# of 64-blocks of eps published); flags[32 + r*32] = done[r]
__global__ __launch_bounds__(256) void k_eps(const float* __restrict__ H22,
                                             const float* __restrict__ bacc,
                                             const float* __restrict__ invLam,
                                             float* __restrict__ eps_g,
                                             float* __restrict__ accfin,
                                             unsigned* __restrict__ flags) {
  const int g = blockIdx.x, t = threadIdx.x;
  if (g == 0) {
    __shared__ float diag[64 * 65];
    for (int b = 0; b < 32; ++b) {
      if (b > 0) {
        while (__hip_atomic_load(&flags[32 + b * 32], __ATOMIC_ACQUIRE,
                                 __HIP_MEMORY_SCOPE_AGENT) == 0u) {
          __builtin_amdgcn_s_sleep(1);
        }
      }
      {
        const int r = t >> 2, c0 = (t & 3) << 4;
        const float* src = H22 + (size_t)(b * 64 + r) * NXI + b * 64 + c0;
#pragma unroll
        for (int s = 0; s < 16; s += 4) {
          const float4 v = *(const float4*)(src + s);
          diag[r * 65 + c0 + s]     = v.x;
          diag[r * 65 + c0 + s + 1] = v.y;
          diag[r * 65 + c0 + s + 2] = v.z;
          diag[r * 65 + c0 + s + 3] = v.w;
        }
      }
      __syncthreads();
      if (t < 64) {
        float s = (b == 0) ? bacc[t] : accfin[b * 64 + t];
        const float il = invLam[b * 64 + t];
        float mye = 0.f;
        for (int j = 0; j < 64; ++j) {
          float xx = s * il;
          xx = fminf(fmaxf(xx, -30.f), 30.f);
          const float e2 = __expf(2.f * xx);
          const float cand = (e2 - 1.f) / (e2 + 1.f);
          const float ej = __shfl(cand, j, 64);
          if (t == j) mye = cand;
          s -= diag[t * 65 + j] * ej;
        }
        eps_g[b * 64 + t] = mye;
      }
      __syncthreads();
      if (t == 0)
        __hip_atomic_store(&flags[0], (unsigned)(b + 1), __ATOMIC_RELEASE,
                           __HIP_MEMORY_SCOPE_AGENT);
    }
  } else {
    const int r = g;           // row-block 1..31
    const int lr = t & 63, q = t >> 6;
    const int grow = r * 64 + lr;
    const float* hrow = H22 + (size_t)grow * NXI;
    float part = 0.f;
    for (int j = 0; j < r; ++j) {
      while (__hip_atomic_load(&flags[0], __ATOMIC_ACQUIRE,
                               __HIP_MEMORY_SCOPE_AGENT) < (unsigned)(j + 1)) {
        __builtin_amdgcn_s_sleep(1);
      }
      const float* ep = eps_g + j * 64 + q * 16;
      const float* hp = hrow + j * 64 + q * 16;
#pragma unroll
      for (int s4 = 0; s4 < 16; s4 += 4) {
        const float4 hv = *(const float4*)(hp + s4);
        const float4 ev = *(const float4*)(ep + s4);
        part -= hv.x * ev.x + hv.y * ev.y + hv.z * ev.z + hv.w * ev.w;
      }
    }
    __shared__ float red[4][64];
    red[q][lr] = part;
    __syncthreads();
    if (t < 64) {
      const float v = bacc[r * 64 + t] + red[0][t] + red[1][t] + red[2][t] + red[3][t];
      accfin[r * 64 + t] = v;
    }
    __syncthreads();
    if (t == 0)
      __hip_atomic_store(&flags[32 + r * 32], 1u, __ATOMIC_RELEASE,
                         __HIP_MEMORY_SCOPE_AGENT);
  }
}

// ---------- 7) E_xi = H31@xi + H32@eps + B2@w ----------
__global__ __launch_bounds__(256) void k_exi(const float* __restrict__ H31,
                                             const float* __restrict__ H32,
                                             const float* __restrict__ B2,
                                             const float* __restrict__ xi,
                                             const float* __restrict__ eps_g,
                                             const float* __restrict__ w,
                                             float* __restrict__ exi) {
  const int t = threadIdx.x;
  const int lane = t & 63;
  const int wv = blockIdx.x * 4 + (t >> 6);
  for (int row = wv; row < NXI; row += 128) {
    const float* fr = H31 + (size_t)row * NXI;
    const float* br = H32 + (size_t)row * LLEN;
    float s = 0.f;
    for (int k0 = 0; k0 < NXI; k0 += 256) {
      const int li = k0 + lane * 4;
      const float4 a = *(const float4*)(fr + li);
      const float4 x4 = *(const float4*)(xi + li);
      const float4 b = *(const float4*)(br + li);
      const float4 e4 = *(const float4*)(eps_g + li);
      s += a.x * x4.x + a.y * x4.y + a.z * x4.z + a.w * x4.w
         + b.x * e4.x + b.y * e4.y + b.z * e4.z + b.w * e4.w;
    }
    const float* b2r = B2 + (size_t)row * NN;
    for (int k0 = 0; k0 < NN; k0 += 256) {
      const int li = k0 + lane * 4;
      const float4 a = *(const float4*)(b2r + li);
      const float4 w4 = *(const float4*)(w + li);
      s += a.x * w4.x + a.y * w4.y + a.z * w4.z + a.w * w4.w;
    }
#pragma unroll
    for (int off = 32; off > 0; off >>= 1) s += __shfl_xor(s, off, 64);
    if (lane == 0) exi[row] = s;
  }
}

// ---------- 8) one Chebyshev iteration: d_new = g1*d + g2*r; x += d_new; r -= A d_new ----------
__global__ __launch_bounds__(256) void k_cheb(const float* __restrict__ E,
                                              const float* __restrict__ din, float* __restrict__ dout,
                                              const float* __restrict__ rin, float* __restrict__ rout,
                                              float* __restrict__ x, float g1, float g2) {
  __shared__ float dn[NXI];
  const int g = blockIdx.x, t = threadIdx.x;
  for (int j = t; j < NXI; j += 256) dn[j] = g1 * din[j] + g2 * rin[j];
  __syncthreads();
  const int lane = t & 63, wv = t >> 6;
#pragma unroll
  for (int rr = 0; rr < 4; ++rr) {
    const int row = g * 16 + wv * 4 + rr;
    const float* er = E + (size_t)row * NXI;
    float s = 0.f;
    for (int k0 = 0; k0 < NXI; k0 += 256) {
      const int li = k0 + lane * 4;
      const float4 ev = *(const float4*)(er + li);
      s += ev.x * dn[li] + ev.y * dn[li + 1] + ev.z * dn[li + 2] + ev.w * dn[li + 3];
    }
#pragma unroll
    for (int off = 32; off > 0; off >>= 1) s += __shfl_xor(s, off, 64);
    if (lane == 0) {
      x[row] += dn[row];
      rout[row] = rin[row] - s;
    }
  }
  if (t < 16) dout[g * 16 + t] = dn[g * 16 + t];
}

// ---------- 9) u = sigmoid-affine(C2@xi + D21@eps + D22@w + bu); also copy xi_next ----------
__global__ __launch_bounds__(256) void k_out(const float* __restrict__ C2,
                                             const float* __restrict__ D21,
                                             const float* __restrict__ D22,
                                             const float* __restrict__ xi,
                                             const float* __restrict__ eps_g,
                                             const float* __restrict__ w,
                                             const float* __restrict__ bu,
                                             const float* __restrict__ x,
                                             float* __restrict__ out) {
  const int t = threadIdx.x, g = blockIdx.x;
  const int gid = g * 256 + t;
  if (gid < NXI) out[MM + gid] = x[gid];
  const int lane = t & 63;
  const int wv = g * 4 + (t >> 6);
  for (int row = wv; row < MM; row += 128) {
    const float* c2r = C2 + (size_t)row * NXI;
    const float* d21r = D21 + (size_t)row * LLEN;
    const float* d22r = D22 + (size_t)row * NN;
    float s = 0.f;
    for (int k0 = 0; k0 < NXI; k0 += 256) {
      const int li = k0 + lane * 4;
      const float4 a = *(const float4*)(c2r + li);
      const float4 xv = *(const float4*)(xi + li);
      const float4 b = *(const float4*)(d21r + li);
      const float4 ev = *(const float4*)(eps_g + li);
      s += a.x * xv.x + a.y * xv.y + a.z * xv.z + a.w * xv.w
         + b.x * ev.x + b.y * ev.y + b.z * ev.z + b.w * ev.w;
    }
    for (int k0 = 0; k0 < NN; k0 += 256) {
      const int li = k0 + lane * 4;
      const float4 a = *(const float4*)(d22r + li);
      const float4 w4 = *(const float4*)(w + li);
      s += a.x * w4.x + a.y * w4.y + a.z * w4.z + a.w * w4.w;
    }
#pragma unroll
    for (int off = 32; off > 0; off >>= 1) s += __shfl_xor(s, off, 64);
    if (lane == 0) {
      const float u = s + bu[row];
      const float sg = 1.f / (1.f + __expf(-u));
      out[row] = 8.0f + 4.8f * sg;
    }
  }
}

// ---------- launch ----------
extern "C" void kernel_launch(void* const* d_in, const int* in_sizes, int n_in,
                              void* d_out, int out_size, void* d_ws, size_t ws_size,
                              hipStream_t stream) {
  (void)in_sizes; (void)n_in; (void)out_size;
  const float* w   = (const float*)d_in[1];
  const float* xi  = (const float*)d_in[2];
  const float* X   = (const float*)d_in[3];
  const float* Y   = (const float*)d_in[4];
  const float* B2  = (const float*)d_in[5];
  const float* C2  = (const float*)d_in[6];
  const float* D21 = (const float*)d_in[7];
  const float* D22 = (const float*)d_in[8];
  const float* D12 = (const float*)d_in[9];
  const float* bu  = (const float*)d_in[10];
  float* out = (float*)d_out;

  // workspace layout (needs ~177 MB)
  char* ws = (char*)d_ws;
  ushort_t* XT = (ushort_t*)ws;                                   // 6144*6144*2   = 75,497,472
  float* H = (float*)(ws + 75497472ull);                          // 6 * 2048^2 *4 = 100,663,296
  float* vecs = (float*)(ws + 75497472ull + 100663296ull);
  float* invLam = vecs;
  float* bacc   = vecs + 2048;
  float* accfin = vecs + 4096;
  float* eps_g  = vecs + 6144;
  float* exi    = vecs + 8192;
  float* xv     = vecs + 10240;
  float* dA     = vecs + 12288;
  float* dB     = vecs + 14336;
  float* rA     = vecs + 16384;
  float* rB     = vecs + 18432;
  unsigned* flags = (unsigned*)(vecs + 20480);                    // 8 KB flag region

  float* H11 = H;                          // becomes E after k_combine
  float* H21 = H + 1ull * 2048 * 2048;
  float* H22 = H + 2ull * 2048 * 2048;
  float* H31 = H + 3ull * 2048 * 2048;
  float* H32 = H + 4ull * 2048 * 2048;
  float* H33 = H + 5ull * 2048 * 2048;

  hipMemsetAsync(flags, 0, 8192, stream);
  hipMemsetAsync(xv, 0, 2048 * sizeof(float), stream);

  k_transpose<<<dim3(96, 96), 256, 0, stream>>>(X, XT);
  k_syrk<<<dim3(16, 16, 6), 256, 0, stream>>>(XT, H);
  k_combine<<<dim3(32, 32), 256, 0, stream>>>(H11, H33, Y);
  k_lam<<<8, 256, 0, stream>>>(H22, invLam);
  k_base<<<32, 256, 0, stream>>>(H21, D12, xi, w, bacc);
  k_eps<<<32, 256, 0, stream>>>(H22, bacc, invLam, eps_g, accfin, flags);
  k_exi<<<32, 256, 0, stream>>>(H31, H32, B2, xi, eps_g, w, exi);

  // Chebyshev on spectral interval [8, 170] (field of values of E: Re in ~[11,153])
  const double lmin = 8.0, lmax = 170.0;
  const double theta = 0.5 * (lmax + lmin), delta = 0.5 * (lmax - lmin);
  const double sigma1 = theta / delta;
  double rho_prev = delta / theta;         // 1/sigma1
  float* din = dA; float* dout_ = dB;
  const float* rin = exi; float* rout = rA;
  for (int i = 0; i < NCHEB; ++i) {
    float g1, g2;
    if (i == 0) { g1 = 0.f; g2 = (float)(1.0 / theta); }
    else {
      const double rho = 1.0 / (2.0 * sigma1 - rho_prev);
      g1 = (float)(rho * rho_prev);
      g2 = (float)(2.0 * rho / delta);
      rho_prev = rho;
    }
    k_cheb<<<128, 256, 0, stream>>>(H11, din, dout_, rin, rout, xv, g1, g2);
    float* tmp = din; din = dout_; dout_ = tmp;
    rin = rout; rout = (rout == rA) ? rB : rA;
  }

  k_out<<<32, 256, 0, stream>>>(C2, D21, D22, xi, eps_g, w, bu, xv, out);
}

// Round 3
// 1089.492 us; speedup vs baseline: 1.2206x; 1.2206x over previous
//
#include <hip/hip_runtime.h>
#include <cstdint>

#define NXI  2048
#define LLEN 2048
#define NN   1024
#define MM   1024
#define SS   6144
#define EPSV 0.001f
#define NCHEB 28

typedef __attribute__((ext_vector_type(8))) __bf16 bf16x8;
typedef __attribute__((ext_vector_type(4))) float  f32x4;
typedef __attribute__((ext_vector_type(8))) unsigned short us8;
typedef unsigned short ushort_t;

// ---------- helpers ----------
__device__ __forceinline__ unsigned short f2bf(float f) {
  unsigned u = __float_as_uint(f);
  unsigned r = (u + 0x7FFFu + ((u >> 16) & 1u)) >> 16;   // RNE
  return (unsigned short)r;
}

__device__ __forceinline__ void gld16(const void* g, void* l) {
  __builtin_amdgcn_global_load_lds((const __attribute__((address_space(1))) void*)g,
                                   (__attribute__((address_space(3))) void*)l,
                                   16, 0, 0);
}

// ---------- 1) transpose + f32->bf16: XT[i][k] = bf16(X[k][i]) ----------
__global__ __launch_bounds__(256) void k_transpose(const float* __restrict__ X,
                                                   ushort_t* __restrict__ XT) {
  __shared__ float tile[64][65];
  const int bx = blockIdx.x, by = blockIdx.y;
  const int t = threadIdx.x;
  const int r = t >> 2, c0 = (t & 3) << 4;
  const float* src = X + (size_t)(by * 64 + r) * SS + bx * 64 + c0;
#pragma unroll
  for (int s = 0; s < 16; s += 4) {
    const float4 v = *(const float4*)(src + s);
    tile[r][c0 + s]     = v.x;
    tile[r][c0 + s + 1] = v.y;
    tile[r][c0 + s + 2] = v.z;
    tile[r][c0 + s + 3] = v.w;
  }
  __syncthreads();
  ushort_t* dst = XT + (size_t)(bx * 64 + r) * SS + by * 64 + c0;
  us8 o0, o1;
#pragma unroll
  for (int s = 0; s < 8; ++s) o0[s] = f2bf(tile[c0 + s][r]);
#pragma unroll
  for (int s = 0; s < 8; ++s) o1[s] = f2bf(tile[c0 + 8 + s][r]);
  *(us8*)dst = o0;
  *(us8*)(dst + 8) = o1;
}

// ---------- 2) H blocks via 256^2-tile 8-wave SYRK, counted-vmcnt pipeline ----------
// z: 0=(0,0)H11 1=(1,0)H21 2=(1,1)H22 3=(2,0)H31 4=(2,1)H32 5=(2,2)H33
// LDS: A[2 dbuf][2 khalf][256 rows][32 k] bf16 (4 units x 16KB), B same. 128KB total.
// Swizzle: read chunk chp = kq ^ ((row>>1)&3); staged via pre-swizzled global source.
// Stage schedule (tile t): ph0: A-kh1(t+1), ph1: B-kh1(t+1), ph2: A-kh0(t+2), ph3: B-kh0(t+2).
// Waits: vmcnt(8) before kh0-reads and before kh1-reads (peeled last tile: 4 / 0).
__global__ __launch_bounds__(512) void k_syrk(const ushort_t* __restrict__ XT,
                                              float* __restrict__ Hws) {
  const int z = blockIdx.z;
  const int Rb = (z >= 3) ? 2 : ((z >= 1) ? 1 : 0);
  const int Cb = z - (Rb * (Rb + 1)) / 2;
  const int bm = blockIdx.y, bn = blockIdx.x;
  if (z == 2 && bn > bm) return;   // H22: lower tiles only
  float* __restrict__ Hout = Hws + (size_t)z * (2048ull * 2048ull);

  const int c = threadIdx.x;             // 0..511
  const int lane = c & 63, wave = c >> 6;
  const int wm = wave >> 2, wn = wave & 3;
  const int rl = lane & 15, kq = lane >> 4;

  __shared__ ushort_t lds[65536];        // 128 KiB
  ushort_t* A_lds = lds;                 // 4 units of 8192 ushorts
  ushort_t* B_lds = lds + 32768;

  const size_t arow0 = (size_t)Rb * 2048 + (size_t)bm * 256;
  const size_t brow0 = (size_t)Cb * 2048 + (size_t)bn * 256;
  const ushort_t* Arows = XT + arow0 * SS;
  const ushort_t* Brows = XT + brow0 * SS;

#define STAGE_UNIT(ROWS, KELEM, UNITPTR)                                      \
  {                                                                           \
    _Pragma("unroll")                                                         \
    for (int q = 0; q < 2; ++q) {                                             \
      const int p  = q * 512 + c;                                             \
      const int r_ = p >> 2, chp_ = p & 3;                                    \
      const int chl_ = chp_ ^ ((r_ >> 1) & 3);                                \
      gld16((ROWS) + (size_t)r_ * SS + (KELEM) + chl_ * 8, (UNITPTR) + p * 8);\
    }                                                                         \
  }

#define LD_A(AU, MG, AARR)                                                    \
  {                                                                           \
    _Pragma("unroll")                                                         \
    for (int m4 = 0; m4 < 4; ++m4) {                                          \
      const int row_ = wm * 128 + ((MG) * 4 + m4) * 16 + rl;                  \
      const int chp_ = kq ^ ((row_ >> 1) & 3);                                \
      AARR[m4] = *(const bf16x8*)((AU) + row_ * 32 + chp_ * 8);               \
    }                                                                         \
  }

#define LD_B(BU, BARR)                                                        \
  {                                                                           \
    _Pragma("unroll")                                                         \
    for (int nf = 0; nf < 4; ++nf) {                                          \
      const int row_ = wn * 64 + nf * 16 + rl;                                \
      const int chp_ = kq ^ ((row_ >> 1) & 3);                                \
      BARR[nf] = *(const bf16x8*)((BU) + row_ * 32 + chp_ * 8);               \
    }                                                                         \
  }

#define DO_MFMA(MG, AARR, BARR)                                               \
  {                                                                           \
    __builtin_amdgcn_s_setprio(1);                                            \
    _Pragma("unroll")                                                         \
    for (int m4 = 0; m4 < 4; ++m4)                                            \
      _Pragma("unroll")                                                       \
      for (int nf = 0; nf < 4; ++nf)                                          \
        acc[(MG) * 4 + m4][nf] = __builtin_amdgcn_mfma_f32_16x16x32_bf16(     \
            AARR[m4], BARR[nf], acc[(MG) * 4 + m4][nf], 0, 0, 0);             \
    __builtin_amdgcn_s_setprio(0);                                            \
  }

  // ---- prologue: stage kh0(0), kh1(0), kh0(1)  (12 loads/thread in flight)
  STAGE_UNIT(Arows, 0,  A_lds + 0 * 8192);   // t0 kh0 -> A[0][0]
  STAGE_UNIT(Brows, 0,  B_lds + 0 * 8192);
  STAGE_UNIT(Arows, 32, A_lds + 1 * 8192);   // t0 kh1 -> A[0][1]
  STAGE_UNIT(Brows, 32, B_lds + 1 * 8192);
  STAGE_UNIT(Arows, 64, A_lds + 2 * 8192);   // t1 kh0 -> A[1][0]
  STAGE_UNIT(Brows, 64, B_lds + 2 * 8192);

  f32x4 acc[8][4] = {};

  for (int t = 0; t < 96; ++t) {
    const int db = t & 1;
    const ushort_t* Au0 = A_lds + (db * 2 + 0) * 8192;
    const ushort_t* Bu0 = B_lds + (db * 2 + 0) * 8192;
    const ushort_t* Au1 = A_lds + (db * 2 + 1) * 8192;
    const ushort_t* Bu1 = B_lds + (db * 2 + 1) * 8192;
    ushort_t* An1 = A_lds + (((db ^ 1) * 2) + 1) * 8192;  // kh1(t+1)
    ushort_t* Bn1 = B_lds + (((db ^ 1) * 2) + 1) * 8192;
    ushort_t* An0 = A_lds + (db * 2 + 0) * 8192;          // kh0(t+2)
    ushort_t* Bn0 = B_lds + (db * 2 + 0) * 8192;

    // ---- boundary wait: kh0(t) resident
    if (t < 95) { asm volatile("s_waitcnt vmcnt(8)" ::: "memory"); }
    else        { asm volatile("s_waitcnt vmcnt(4)" ::: "memory"); }
    __builtin_amdgcn_s_barrier();

    bf16x8 aA[4], bB[4];
    // ---- ph0: kh0, mgroup0 ; stage A-kh1(t+1)
    LD_A(Au0, 0, aA); LD_B(Bu0, bB);
    if (t < 95) STAGE_UNIT(Arows, (t + 1) * 64 + 32, An1);
    __builtin_amdgcn_s_barrier();
    DO_MFMA(0, aA, bB);
    __builtin_amdgcn_s_barrier();

    // ---- ph1: kh0, mgroup1 ; stage B-kh1(t+1)  (reuse bB)
    LD_A(Au0, 1, aA);
    if (t < 95) STAGE_UNIT(Brows, (t + 1) * 64 + 32, Bn1);
    __builtin_amdgcn_s_barrier();
    DO_MFMA(1, aA, bB);

    // ---- mid wait: kh1(t) resident
    if (t < 95) { asm volatile("s_waitcnt vmcnt(8)" ::: "memory"); }
    else        { asm volatile("s_waitcnt vmcnt(0)" ::: "memory"); }
    __builtin_amdgcn_s_barrier();

    // ---- ph2: kh1, mgroup0 ; stage A-kh0(t+2)
    LD_A(Au1, 0, aA); LD_B(Bu1, bB);
    if (t < 94) STAGE_UNIT(Arows, (t + 2) * 64, An0);
    __builtin_amdgcn_s_barrier();
    DO_MFMA(0, aA, bB);
    __builtin_amdgcn_s_barrier();

    // ---- ph3: kh1, mgroup1 ; stage B-kh0(t+2)
    LD_A(Au1, 1, aA);
    if (t < 94) STAGE_UNIT(Brows, (t + 2) * 64, Bn0);
    __builtin_amdgcn_s_barrier();
    DO_MFMA(1, aA, bB);
    __builtin_amdgcn_s_barrier();
  }

  // ---- epilogue: C write
  const int cr = kq << 2, cc = rl;
  const bool dg = (Rb == Cb);
#pragma unroll
  for (int mf = 0; mf < 8; ++mf) {
#pragma unroll
    for (int nf = 0; nf < 4; ++nf) {
#pragma unroll
      for (int v = 0; v < 4; ++v) {
        const int row = bm * 256 + wm * 128 + mf * 16 + cr + v;
        const int col = bn * 256 + wn * 64 + nf * 16 + cc;
        float val = acc[mf][nf][v];
        if (dg && row == col) val += EPSV;
        Hout[(size_t)row * 2048 + col] = val;
      }
    }
  }
#undef STAGE_UNIT
#undef LD_A
#undef LD_B
#undef DO_MFMA
}

// ---------- 3) E = 0.5*(H11 + H33 + Y - Y^T), in-place into H11 ----------
__global__ __launch_bounds__(256) void k_combine(float* __restrict__ H0,
                                                 const float* __restrict__ H5,
                                                 const float* __restrict__ Y) {
  __shared__ float yt[64][65];
  const int bx = blockIdx.x, by = blockIdx.y;
  const int t = threadIdx.x;
  const int r = t >> 2, c0 = (t & 3) << 4;
  const float* ys = Y + (size_t)(bx * 64 + r) * 2048 + by * 64 + c0;
#pragma unroll
  for (int s = 0; s < 16; s += 4) {
    const float4 v = *(const float4*)(ys + s);
    yt[r][c0 + s]     = v.x;
    yt[r][c0 + s + 1] = v.y;
    yt[r][c0 + s + 2] = v.z;
    yt[r][c0 + s + 3] = v.w;
  }
  __syncthreads();
  const size_t base = (size_t)(by * 64 + r) * 2048 + bx * 64 + c0;
#pragma unroll
  for (int s = 0; s < 16; s += 4) {
    const float4 a = *(const float4*)(H0 + base + s);
    const float4 b = *(const float4*)(H5 + base + s);
    const float4 y = *(const float4*)(Y + base + s);
    float4 e;
    e.x = 0.5f * (a.x + b.x + y.x - yt[c0 + s][r]);
    e.y = 0.5f * (a.y + b.y + y.y - yt[c0 + s + 1][r]);
    e.z = 0.5f * (a.z + b.z + y.z - yt[c0 + s + 2][r]);
    e.w = 0.5f * (a.w + b.w + y.w - yt[c0 + s + 3][r]);
    *(float4*)(H0 + base + s) = e;
  }
}

// ---------- 4) invLam[i] = 1/(0.5*H22[i][i]) ----------
__global__ __launch_bounds__(256) void k_lam(const float* __restrict__ H22,
                                             float* __restrict__ invLam) {
  const int i = blockIdx.x * 256 + threadIdx.x;
  if (i < NXI) invLam[i] = 2.0f / H22[(size_t)i * 2048 + i];
}

// ---------- 5) base[i] = -(H21@xi)[i] + (D12@w)[i] ----------
__global__ __launch_bounds__(256) void k_base(const float* __restrict__ H21,
                                              const float* __restrict__ D12,
                                              const float* __restrict__ xi,
                                              const float* __restrict__ w,
                                              float* __restrict__ bacc) {
  const int t = threadIdx.x;
  const int lane = t & 63;
  const int wv = blockIdx.x * 4 + (t >> 6);
  for (int row = wv; row < LLEN; row += 512) {
    const float* hr = H21 + (size_t)row * NXI;
    float s = 0.f;
    for (int k0 = 0; k0 < NXI; k0 += 256) {
      const int li = k0 + lane * 4;
      const float4 h = *(const float4*)(hr + li);
      const float4 x4 = *(const float4*)(xi + li);
      s += h.x * x4.x + h.y * x4.y + h.z * x4.z + h.w * x4.w;
    }
    const float* dr = D12 + (size_t)row * NN;
    float s2 = 0.f;
    for (int k0 = 0; k0 < NN; k0 += 256) {
      const int li = k0 + lane * 4;
      const float4 h = *(const float4*)(dr + li);
      const float4 x4 = *(const float4*)(w + li);
      s2 += h.x * x4.x + h.y * x4.y + h.z * x4.z + h.w * x4.w;
    }
    float tot = s2 - s;
#pragma unroll
    for (int off = 32; off > 0; off >>= 1) tot += __shfl_xor(tot, off, 64);
    if (lane == 0) bacc[row] = tot;
  }
}

// ---------- 6) sequential eps solve: producer/consumer spin kernel ----------
__global__ __launch_bounds__(256) void k_eps(const float* __restrict__ H22,
                                             const float* __restrict__ bacc,
                                             const float* __restrict__ invLam,
                                             float* __restrict__ eps_g,
                                             float* __restrict__ accfin,
                                             unsigned* __restrict__ flags) {
  const int g = blockIdx.x, t = threadIdx.x;
  if (g == 0) {
    __shared__ float diag[64 * 65];
    for (int b = 0; b < 32; ++b) {
      if (b > 0) {
        while (__hip_atomic_load(&flags[32 + b * 32], __ATOMIC_ACQUIRE,
                                 __HIP_MEMORY_SCOPE_AGENT) == 0u) {
          __builtin_amdgcn_s_sleep(1);
        }
      }
      {
        const int r = t >> 2, c0 = (t & 3) << 4;
        const float* src = H22 + (size_t)(b * 64 + r) * NXI + b * 64 + c0;
#pragma unroll
        for (int s = 0; s < 16; s += 4) {
          const float4 v = *(const float4*)(src + s);
          diag[r * 65 + c0 + s]     = v.x;
          diag[r * 65 + c0 + s + 1] = v.y;
          diag[r * 65 + c0 + s + 2] = v.z;
          diag[r * 65 + c0 + s + 3] = v.w;
        }
      }
      __syncthreads();
      if (t < 64) {
        float s = (b == 0) ? bacc[t] : accfin[b * 64 + t];
        const float il = invLam[b * 64 + t];
        float mye = 0.f;
        for (int j = 0; j < 64; ++j) {
          float xx = s * il;
          xx = fminf(fmaxf(xx, -30.f), 30.f);
          const float e2 = __expf(2.f * xx);
          const float cand = (e2 - 1.f) / (e2 + 1.f);
          const float ej = __shfl(cand, j, 64);
          if (t == j) mye = cand;
          s -= diag[t * 65 + j] * ej;
        }
        eps_g[b * 64 + t] = mye;
      }
      __syncthreads();
      if (t == 0)
        __hip_atomic_store(&flags[0], (unsigned)(b + 1), __ATOMIC_RELEASE,
                           __HIP_MEMORY_SCOPE_AGENT);
    }
  } else {
    const int r = g;           // row-block 1..31
    const int lr = t & 63, q = t >> 6;
    const int grow = r * 64 + lr;
    const float* hrow = H22 + (size_t)grow * NXI;
    float part = 0.f;
    for (int j = 0; j < r; ++j) {
      while (__hip_atomic_load(&flags[0], __ATOMIC_ACQUIRE,
                               __HIP_MEMORY_SCOPE_AGENT) < (unsigned)(j + 1)) {
        __builtin_amdgcn_s_sleep(1);
      }
      const float* ep = eps_g + j * 64 + q * 16;
      const float* hp = hrow + j * 64 + q * 16;
#pragma unroll
      for (int s4 = 0; s4 < 16; s4 += 4) {
        const float4 hv = *(const float4*)(hp + s4);
        const float4 ev = *(const float4*)(ep + s4);
        part -= hv.x * ev.x + hv.y * ev.y + hv.z * ev.z + hv.w * ev.w;
      }
    }
    __shared__ float red[4][64];
    red[q][lr] = part;
    __syncthreads();
    if (t < 64) {
      const float v = bacc[r * 64 + t] + red[0][t] + red[1][t] + red[2][t] + red[3][t];
      accfin[r * 64 + t] = v;
    }
    __syncthreads();
    if (t == 0)
      __hip_atomic_store(&flags[32 + r * 32], 1u, __ATOMIC_RELEASE,
                         __HIP_MEMORY_SCOPE_AGENT);
  }
}

// ---------- 7) E_xi = H31@xi + H32@eps + B2@w ----------
__global__ __launch_bounds__(256) void k_exi(const float* __restrict__ H31,
                                             const float* __restrict__ H32,
                                             const float* __restrict__ B2,
                                             const float* __restrict__ xi,
                                             const float* __restrict__ eps_g,
                                             const float* __restrict__ w,
                                             float* __restrict__ exi) {
  const int t = threadIdx.x;
  const int lane = t & 63;
  const int wv = blockIdx.x * 4 + (t >> 6);
  for (int row = wv; row < NXI; row += 512) {
    const float* fr = H31 + (size_t)row * NXI;
    const float* br = H32 + (size_t)row * LLEN;
    float s = 0.f;
    for (int k0 = 0; k0 < NXI; k0 += 256) {
      const int li = k0 + lane * 4;
      const float4 a = *(const float4*)(fr + li);
      const float4 x4 = *(const float4*)(xi + li);
      const float4 b = *(const float4*)(br + li);
      const float4 e4 = *(const float4*)(eps_g + li);
      s += a.x * x4.x + a.y * x4.y + a.z * x4.z + a.w * x4.w
         + b.x * e4.x + b.y * e4.y + b.z * e4.z + b.w * e4.w;
    }
    const float* b2r = B2 + (size_t)row * NN;
    for (int k0 = 0; k0 < NN; k0 += 256) {
      const int li = k0 + lane * 4;
      const float4 a = *(const float4*)(b2r + li);
      const float4 w4 = *(const float4*)(w + li);
      s += a.x * w4.x + a.y * w4.y + a.z * w4.z + a.w * w4.w;
    }
#pragma unroll
    for (int off = 32; off > 0; off >>= 1) s += __shfl_xor(s, off, 64);
    if (lane == 0) exi[row] = s;
  }
}

// ---------- 8) one Chebyshev iteration ----------
__global__ __launch_bounds__(256) void k_cheb(const float* __restrict__ E,
                                              const float* __restrict__ din, float* __restrict__ dout,
                                              const float* __restrict__ rin, float* __restrict__ rout,
                                              float* __restrict__ x, float g1, float g2) {
  __shared__ float dn[NXI];
  const int g = blockIdx.x, t = threadIdx.x;
  for (int j = t; j < NXI; j += 256) dn[j] = g1 * din[j] + g2 * rin[j];
  __syncthreads();
  const int lane = t & 63, wv = t >> 6;
#pragma unroll
  for (int rr = 0; rr < 4; ++rr) {
    const int row = g * 16 + wv * 4 + rr;
    const float* er = E + (size_t)row * NXI;
    float s = 0.f;
    for (int k0 = 0; k0 < NXI; k0 += 256) {
      const int li = k0 + lane * 4;
      const float4 ev = *(const float4*)(er + li);
      s += ev.x * dn[li] + ev.y * dn[li + 1] + ev.z * dn[li + 2] + ev.w * dn[li + 3];
    }
#pragma unroll
    for (int off = 32; off > 0; off >>= 1) s += __shfl_xor(s, off, 64);
    if (lane == 0) {
      x[row] += dn[row];
      rout[row] = rin[row] - s;
    }
  }
  if (t < 16) dout[g * 16 + t] = dn[g * 16 + t];
}

// ---------- 9) outputs ----------
__global__ __launch_bounds__(256) void k_out(const float* __restrict__ C2,
                                             const float* __restrict__ D21,
                                             const float* __restrict__ D22,
                                             const float* __restrict__ xi,
                                             const float* __restrict__ eps_g,
                                             const float* __restrict__ w,
                                             const float* __restrict__ bu,
                                             const float* __restrict__ x,
                                             float* __restrict__ out) {
  const int t = threadIdx.x, g = blockIdx.x;
  const int gid = g * 256 + t;
  if (gid < NXI) out[MM + gid] = x[gid];
  const int lane = t & 63;
  const int wv = g * 4 + (t >> 6);
  for (int row = wv; row < MM; row += 512) {
    const float* c2r = C2 + (size_t)row * NXI;
    const float* d21r = D21 + (size_t)row * LLEN;
    const float* d22r = D22 + (size_t)row * NN;
    float s = 0.f;
    for (int k0 = 0; k0 < NXI; k0 += 256) {
      const int li = k0 + lane * 4;
      const float4 a = *(const float4*)(c2r + li);
      const float4 xv = *(const float4*)(xi + li);
      const float4 b = *(const float4*)(d21r + li);
      const float4 ev = *(const float4*)(eps_g + li);
      s += a.x * xv.x + a.y * xv.y + a.z * xv.z + a.w * xv.w
         + b.x * ev.x + b.y * ev.y + b.z * ev.z + b.w * ev.w;
    }
    for (int k0 = 0; k0 < NN; k0 += 256) {
      const int li = k0 + lane * 4;
      const float4 a = *(const float4*)(d22r + li);
      const float4 w4 = *(const float4*)(w + li);
      s += a.x * w4.x + a.y * w4.y + a.z * w4.z + a.w * w4.w;
    }
#pragma unroll
    for (int off = 32; off > 0; off >>= 1) s += __shfl_xor(s, off, 64);
    if (lane == 0) {
      const float u = s + bu[row];
      const float sg = 1.f / (1.f + __expf(-u));
      out[row] = 8.0f + 4.8f * sg;
    }
  }
}

// ---------- launch ----------
extern "C" void kernel_launch(void* const* d_in, const int* in_sizes, int n_in,
                              void* d_out, int out_size, void* d_ws, size_t ws_size,
                              hipStream_t stream) {
  (void)in_sizes; (void)n_in; (void)out_size;
  const float* w   = (const float*)d_in[1];
  const float* xi  = (const float*)d_in[2];
  const float* X   = (const float*)d_in[3];
  const float* Y   = (const float*)d_in[4];
  const float* B2  = (const float*)d_in[5];
  const float* C2  = (const float*)d_in[6];
  const float* D21 = (const float*)d_in[7];
  const float* D22 = (const float*)d_in[8];
  const float* D12 = (const float*)d_in[9];
  const float* bu  = (const float*)d_in[10];
  float* out = (float*)d_out;

  char* ws = (char*)d_ws;
  ushort_t* XT = (ushort_t*)ws;                                   // 75,497,472 B
  float* H = (float*)(ws + 75497472ull);                          // 100,663,296 B
  float* vecs = (float*)(ws + 75497472ull + 100663296ull);
  float* invLam = vecs;
  float* bacc   = vecs + 2048;
  float* accfin = vecs + 4096;
  float* eps_g  = vecs + 6144;
  float* exi    = vecs + 8192;
  float* xv     = vecs + 10240;
  float* dA     = vecs + 12288;
  float* dB     = vecs + 14336;
  float* rA     = vecs + 16384;
  float* rB     = vecs + 18432;
  unsigned* flags = (unsigned*)(vecs + 20480);

  float* H11 = H;                          // becomes E after k_combine
  float* H21 = H + 1ull * 2048 * 2048;
  float* H22 = H + 2ull * 2048 * 2048;
  float* H31 = H + 3ull * 2048 * 2048;
  float* H32 = H + 4ull * 2048 * 2048;
  float* H33 = H + 5ull * 2048 * 2048;

  hipMemsetAsync(flags, 0, 8192, stream);
  hipMemsetAsync(xv, 0, 2048 * sizeof(float), stream);

  k_transpose<<<dim3(96, 96), 256, 0, stream>>>(X, XT);
  k_syrk<<<dim3(8, 8, 6), 512, 0, stream>>>(XT, H);
  k_combine<<<dim3(32, 32), 256, 0, stream>>>(H11, H33, Y);
  k_lam<<<8, 256, 0, stream>>>(H22, invLam);
  k_base<<<128, 256, 0, stream>>>(H21, D12, xi, w, bacc);
  k_eps<<<32, 256, 0, stream>>>(H22, bacc, invLam, eps_g, accfin, flags);
  k_exi<<<128, 256, 0, stream>>>(H31, H32, B2, xi, eps_g, w, exi);

  // Chebyshev on spectral interval [8, 170]
  const double lmin = 8.0, lmax = 170.0;
  const double theta = 0.5 * (lmax + lmin), delta = 0.5 * (lmax - lmin);
  const double sigma1 = theta / delta;
  double rho_prev = delta / theta;
  float* din = dA; float* dout_ = dB;
  const float* rin = exi; float* rout = rA;
  for (int i = 0; i < NCHEB; ++i) {
    float g1, g2;
    if (i == 0) { g1 = 0.f; g2 = (float)(1.0 / theta); }
    else {
      const double rho = 1.0 / (2.0 * sigma1 - rho_prev);
      g1 = (float)(rho * rho_prev);
      g2 = (float)(2.0 * rho / delta);
      rho_prev = rho;
    }
    k_cheb<<<128, 256, 0, stream>>>(H11, din, dout_, rin, rout, xv, g1, g2);
    float* tmp = din; din = dout_; dout_ = tmp;
    rin = rout; rout = (rout == rA) ? rB : rA;
  }

  k_out<<<128, 256, 0, stream>>>(C2, D21, D22, xi, eps_g, w, bu, xv, out);
}

// Round 6
// 1000.594 us; speedup vs baseline: 1.3291x; 1.0888x over previous
//
#include <hip/hip_runtime.h>
#include <cstdint>

#define NXI  2048
#define LLEN 2048
#define NN   1024
#define MM   1024
#define SS   6144
#define EPSV 0.001f
#define NCHEB 14

typedef __attribute__((ext_vector_type(8))) __bf16 bf16x8;
typedef __attribute__((ext_vector_type(4))) float  f32x4;
typedef __attribute__((ext_vector_type(8))) unsigned short us8;
typedef unsigned short ushort_t;

struct Coefs { float g1[NCHEB]; float g2[NCHEB]; };

// ---------- helpers ----------
__device__ __forceinline__ unsigned short f2bf(float f) {
  unsigned u = __float_as_uint(f);
  unsigned r = (u + 0x7FFFu + ((u >> 16) & 1u)) >> 16;   // RNE
  return (unsigned short)r;
}

__device__ __forceinline__ void gld16(const void* g, void* l) {
  __builtin_amdgcn_global_load_lds((const __attribute__((address_space(1))) void*)g,
                                   (__attribute__((address_space(3))) void*)l,
                                   16, 0, 0);
}

__device__ __forceinline__ void gridbar(unsigned* cnt, unsigned target) {
  __threadfence();
  __syncthreads();
  if (threadIdx.x == 0) {
    __hip_atomic_fetch_add(cnt, 1u, __ATOMIC_ACQ_REL, __HIP_MEMORY_SCOPE_AGENT);
    while (__hip_atomic_load(cnt, __ATOMIC_ACQUIRE, __HIP_MEMORY_SCOPE_AGENT) < target)
      __builtin_amdgcn_s_sleep(2);
  }
  __syncthreads();
}

// ---------- 1) transpose + f32->bf16: XT[i][k] = bf16(X[k][i]) ----------
__global__ __launch_bounds__(256) void k_transpose(const float* __restrict__ X,
                                                   ushort_t* __restrict__ XT) {
  __shared__ float tile[64][65];
  const int bx = blockIdx.x, by = blockIdx.y;
  const int t = threadIdx.x;
  const int r = t >> 2, c0 = (t & 3) << 4;
  const float* src = X + (size_t)(by * 64 + r) * SS + bx * 64 + c0;
#pragma unroll
  for (int s = 0; s < 16; s += 4) {
    const float4 v = *(const float4*)(src + s);
    tile[r][c0 + s]     = v.x;
    tile[r][c0 + s + 1] = v.y;
    tile[r][c0 + s + 2] = v.z;
    tile[r][c0 + s + 3] = v.w;
  }
  __syncthreads();
  ushort_t* dst = XT + (size_t)(bx * 64 + r) * SS + by * 64 + c0;
  us8 o0, o1;
#pragma unroll
  for (int s = 0; s < 8; ++s) o0[s] = f2bf(tile[c0 + s][r]);
#pragma unroll
  for (int s = 0; s < 8; ++s) o1[s] = f2bf(tile[c0 + 8 + s][r]);
  *(us8*)dst = o0;
  *(us8*)(dst + 8) = o1;
}

// ---------- 2) H blocks via 256^2-tile 8-wave SYRK, counted-vmcnt pipeline ----------
// 2 barriers per K-64 tile; XCD-chunked block swizzle (384 blocks, %8==0 bijective).
__global__ __launch_bounds__(512) void k_syrk(const ushort_t* __restrict__ XT,
                                              float* __restrict__ Hws) {
  int bid = blockIdx.z * 64 + blockIdx.y * 8 + blockIdx.x;
  bid = (bid & 7) * 48 + (bid >> 3);           // XCD chunking: 48 consecutive tiles/XCD
  const int z = bid >> 6;
  const int rem = bid & 63;
  const int bm = rem >> 3, bn = rem & 7;
  const int Rb = (z >= 3) ? 2 : ((z >= 1) ? 1 : 0);
  const int Cb = z - (Rb * (Rb + 1)) / 2;
  if (z == 2 && bn > bm) return;               // H22: lower tiles only
  float* __restrict__ Hout = Hws + (size_t)z * (2048ull * 2048ull);

  const int c = threadIdx.x;
  const int lane = c & 63, wave = c >> 6;
  const int wm = wave >> 2, wn = wave & 3;
  const int rl = lane & 15, kq = lane >> 4;

  __shared__ ushort_t lds[65536];        // 128 KiB
  ushort_t* A_lds = lds;
  ushort_t* B_lds = lds + 32768;

  const size_t arow0 = (size_t)Rb * 2048 + (size_t)bm * 256;
  const size_t brow0 = (size_t)Cb * 2048 + (size_t)bn * 256;
  const ushort_t* Arows = XT + arow0 * SS;
  const ushort_t* Brows = XT + brow0 * SS;

#define STAGE_UNIT(ROWS, KELEM, UNITPTR)                                      \
  {                                                                           \
    _Pragma("unroll")                                                         \
    for (int q = 0; q < 2; ++q) {                                             \
      const int p  = q * 512 + c;                                             \
      const int r_ = p >> 2, chp_ = p & 3;                                    \
      const int chl_ = chp_ ^ ((r_ >> 1) & 3);                                \
      gld16((ROWS) + (size_t)r_ * SS + (KELEM) + chl_ * 8, (UNITPTR) + p * 8);\
    }                                                                         \
  }

#define LD_A(AU, MG, AARR)                                                    \
  {                                                                           \
    _Pragma("unroll")                                                         \
    for (int m4 = 0; m4 < 4; ++m4) {                                          \
      const int row_ = wm * 128 + ((MG) * 4 + m4) * 16 + rl;                  \
      const int chp_ = kq ^ ((row_ >> 1) & 3);                                \
      AARR[m4] = *(const bf16x8*)((AU) + row_ * 32 + chp_ * 8);               \
    }                                                                         \
  }

#define LD_B(BU, BARR)                                                        \
  {                                                                           \
    _Pragma("unroll")                                                         \
    for (int nf = 0; nf < 4; ++nf) {                                          \
      const int row_ = wn * 64 + nf * 16 + rl;                                \
      const int chp_ = kq ^ ((row_ >> 1) & 3);                                \
      BARR[nf] = *(const bf16x8*)((BU) + row_ * 32 + chp_ * 8);               \
    }                                                                         \
  }

#define DO_MFMA(MG, AARR, BARR)                                               \
  {                                                                           \
    __builtin_amdgcn_s_setprio(1);                                            \
    _Pragma("unroll")                                                         \
    for (int m4 = 0; m4 < 4; ++m4)                                            \
      _Pragma("unroll")                                                       \
      for (int nf = 0; nf < 4; ++nf)                                          \
        acc[(MG) * 4 + m4][nf] = __builtin_amdgcn_mfma_f32_16x16x32_bf16(     \
            AARR[m4], BARR[nf], acc[(MG) * 4 + m4][nf], 0, 0, 0);             \
    __builtin_amdgcn_s_setprio(0);                                            \
  }

  // prologue: kh0(0), kh1(0), kh0(1)  -> 12 loads/thread in flight
  STAGE_UNIT(Arows, 0,  A_lds + 0 * 8192);
  STAGE_UNIT(Brows, 0,  B_lds + 0 * 8192);
  STAGE_UNIT(Arows, 32, A_lds + 1 * 8192);
  STAGE_UNIT(Brows, 32, B_lds + 1 * 8192);
  STAGE_UNIT(Arows, 64, A_lds + 2 * 8192);
  STAGE_UNIT(Brows, 64, B_lds + 2 * 8192);

  f32x4 acc[8][4] = {};

  for (int t = 0; t < 96; ++t) {
    const int db = t & 1;
    const ushort_t* Au0 = A_lds + (db * 2 + 0) * 8192;
    const ushort_t* Bu0 = B_lds + (db * 2 + 0) * 8192;
    const ushort_t* Au1 = A_lds + (db * 2 + 1) * 8192;
    const ushort_t* Bu1 = B_lds + (db * 2 + 1) * 8192;
    ushort_t* An1 = A_lds + (((db ^ 1) * 2) + 1) * 8192;   // kh1(t+1)
    ushort_t* Bn1 = B_lds + (((db ^ 1) * 2) + 1) * 8192;
    ushort_t* An0 = A_lds + (db * 2 + 0) * 8192;           // kh0(t+2)
    ushort_t* Bn0 = B_lds + (db * 2 + 0) * 8192;

    if (t < 95) { asm volatile("s_waitcnt vmcnt(8)" ::: "memory"); }
    else        { asm volatile("s_waitcnt vmcnt(4)" ::: "memory"); }
    __builtin_amdgcn_s_barrier();

    bf16x8 aA[4], bB[4];
    LD_A(Au0, 0, aA); LD_B(Bu0, bB);
    if (t < 95) { STAGE_UNIT(Arows, (t + 1) * 64 + 32, An1);
                  STAGE_UNIT(Brows, (t + 1) * 64 + 32, Bn1); }
    DO_MFMA(0, aA, bB);
    LD_A(Au0, 1, aA);
    DO_MFMA(1, aA, bB);

    if (t < 95) { asm volatile("s_waitcnt vmcnt(8)" ::: "memory"); }
    else        { asm volatile("s_waitcnt vmcnt(0)" ::: "memory"); }
    __builtin_amdgcn_s_barrier();

    LD_A(Au1, 0, aA); LD_B(Bu1, bB);
    if (t < 94) { STAGE_UNIT(Arows, (t + 2) * 64, An0);
                  STAGE_UNIT(Brows, (t + 2) * 64, Bn0); }
    DO_MFMA(0, aA, bB);
    LD_A(Au1, 1, aA);
    DO_MFMA(1, aA, bB);
  }

  const int cr = kq << 2, cc = rl;
  const bool dg = (Rb == Cb);
#pragma unroll
  for (int mf = 0; mf < 8; ++mf) {
#pragma unroll
    for (int nf = 0; nf < 4; ++nf) {
#pragma unroll
      for (int v = 0; v < 4; ++v) {
        const int row = bm * 256 + wm * 128 + mf * 16 + cr + v;
        const int col = bn * 256 + wn * 64 + nf * 16 + cc;
        float val = acc[mf][nf][v];
        if (dg && row == col) val += EPSV;
        Hout[(size_t)row * 2048 + col] = val;
      }
    }
  }
#undef STAGE_UNIT
#undef LD_A
#undef LD_B
#undef DO_MFMA
}

// ---------- 3) fused: E-combine (blocks 0..1023) | invLam (1024..1031) | base (1032..1159) ----------
__global__ __launch_bounds__(256) void k_mid(float* __restrict__ H0,
                                             const float* __restrict__ H5,
                                             const float* __restrict__ Y,
                                             const float* __restrict__ H22,
                                             float* __restrict__ invLam,
                                             const float* __restrict__ H21,
                                             const float* __restrict__ D12,
                                             const float* __restrict__ xi,
                                             const float* __restrict__ w,
                                             float* __restrict__ bacc) {
  const int bid = blockIdx.x, t = threadIdx.x;
  if (bid < 1024) {
    __shared__ float yt[64][65];
    const int bx = bid & 31, by = bid >> 5;
    const int r = t >> 2, c0 = (t & 3) << 4;
    const float* ys = Y + (size_t)(bx * 64 + r) * 2048 + by * 64 + c0;
#pragma unroll
    for (int s = 0; s < 16; s += 4) {
      const float4 v = *(const float4*)(ys + s);
      yt[r][c0 + s]     = v.x;
      yt[r][c0 + s + 1] = v.y;
      yt[r][c0 + s + 2] = v.z;
      yt[r][c0 + s + 3] = v.w;
    }
    __syncthreads();
    const size_t base = (size_t)(by * 64 + r) * 2048 + bx * 64 + c0;
#pragma unroll
    for (int s = 0; s < 16; s += 4) {
      const float4 a = *(const float4*)(H0 + base + s);
      const float4 b = *(const float4*)(H5 + base + s);
      const float4 y = *(const float4*)(Y + base + s);
      float4 e;
      e.x = 0.5f * (a.x + b.x + y.x - yt[c0 + s][r]);
      e.y = 0.5f * (a.y + b.y + y.y - yt[c0 + s + 1][r]);
      e.z = 0.5f * (a.z + b.z + y.z - yt[c0 + s + 2][r]);
      e.w = 0.5f * (a.w + b.w + y.w - yt[c0 + s + 3][r]);
      *(float4*)(H0 + base + s) = e;
    }
  } else if (bid < 1032) {
    const int i = (bid - 1024) * 256 + t;
    // exponent scale for tanh via 2^x: 4*log2(e)/H22[i][i]
    invLam[i] = 5.770780163555854f / H22[(size_t)i * 2048 + i];
  } else {
    const int lane = t & 63;
    const int wv = (bid - 1032) * 4 + (t >> 6);
    for (int row = wv; row < LLEN; row += 512) {
      const float* hr = H21 + (size_t)row * NXI;
      float s = 0.f;
      for (int k0 = 0; k0 < NXI; k0 += 256) {
        const int li = k0 + lane * 4;
        const float4 h = *(const float4*)(hr + li);
        const float4 x4 = *(const float4*)(xi + li);
        s += h.x * x4.x + h.y * x4.y + h.z * x4.z + h.w * x4.w;
      }
      const float* dr = D12 + (size_t)row * NN;
      float s2 = 0.f;
      for (int k0 = 0; k0 < NN; k0 += 256) {
        const int li = k0 + lane * 4;
        const float4 h = *(const float4*)(dr + li);
        const float4 x4 = *(const float4*)(w + li);
        s2 += h.x * x4.x + h.y * x4.y + h.z * x4.z + h.w * x4.w;
      }
      float tot = s2 - s;
#pragma unroll
      for (int off = 32; off > 0; off >>= 1) tot += __shfl_xor(tot, off, 64);
      if (lane == 0) bacc[row] = tot;
    }
  }
}

// ---------- 4) eps solve: producer applies last chunk itself; consumers handle j<=b-2 ----------
// flags[0] = pub count; flags[64 + r*16] = consumer r done
__global__ __launch_bounds__(256) void k_eps(const float* __restrict__ H22,
                                             const float* __restrict__ bacc,
                                             const float* __restrict__ invLam,
                                             float* __restrict__ eps_g,
                                             float* __restrict__ accfin,
                                             unsigned* __restrict__ flags) {
  __shared__ float diagL[2][64 * 65];
  __shared__ float chunkL[2][64 * 68];
  __shared__ float epsL[64];
  __shared__ float redL[256];
  const int g = blockIdx.x, t = threadIdx.x;
  if (g == 0) {
    const int r_ = t >> 2, c_ = (t & 3) << 4;
    {  // preload diag[0]
      const float* src = H22 + (size_t)r_ * 2048 + c_;
#pragma unroll
      for (int s4 = 0; s4 < 16; s4 += 4) {
        const float4 v = *(const float4*)(src + s4);
        diagL[0][r_ * 65 + c_ + s4]     = v.x;
        diagL[0][r_ * 65 + c_ + s4 + 1] = v.y;
        diagL[0][r_ * 65 + c_ + s4 + 2] = v.z;
        diagL[0][r_ * 65 + c_ + s4 + 3] = v.w;
      }
    }
    __syncthreads();
    for (int b = 0; b < 32; ++b) {
      const int cur = b & 1, nxt = cur ^ 1;
      float4 pd[4], pc[4];
      if (b < 31) {  // prefetch next diag + chunk into regs
        const float* ds = H22 + (size_t)((b + 1) * 64 + r_) * 2048 + (b + 1) * 64 + c_;
        const float* cs = H22 + (size_t)((b + 1) * 64 + r_) * 2048 + b * 64 + c_;
#pragma unroll
        for (int s4 = 0; s4 < 4; ++s4) {
          pd[s4] = *(const float4*)(ds + s4 * 4);
          pc[s4] = *(const float4*)(cs + s4 * 4);
        }
      }
      float sv = 0.f;
      if (b == 0) {
        if (t < 64) sv = bacc[t];
      } else {
        while (__hip_atomic_load(&flags[64 + b * 16], __ATOMIC_ACQUIRE,
                                 __HIP_MEMORY_SCOPE_AGENT) == 0u)
          __builtin_amdgcn_s_sleep(1);
        const int row = t >> 2, q = t & 3;
        float part = 0.f;
#pragma unroll
        for (int i = 0; i < 16; ++i)
          part += chunkL[cur][row * 68 + q * 16 + i] * epsL[q * 16 + i];
        redL[t] = part;
        __syncthreads();
        if (t < 64)
          sv = accfin[b * 64 + t] -
               (redL[t * 4] + redL[t * 4 + 1] + redL[t * 4 + 2] + redL[t * 4 + 3]);
      }
      __syncthreads();
      if (t < 64) {  // serial diagonal solve, wave0 only
        const float il2 = invLam[b * 64 + t];
        float s = sv, mye = 0.f;
        for (int j = 0; j < 64; ++j) {
          const float xarg = s * il2;
          float e2; asm("v_exp_f32 %0, %1" : "=v"(e2) : "v"(xarg));
          const float den = e2 + 1.f;
          float rc; asm("v_rcp_f32 %0, %1" : "=v"(rc) : "v"(den));
          const float cand = 1.f - 2.f * rc;
          const float ej = __int_as_float(
              __builtin_amdgcn_readlane(__float_as_int(cand), j));
          if (t == j) mye = ej;
          s -= diagL[cur][t * 65 + j] * ej;
        }
        epsL[t] = mye;
        eps_g[b * 64 + t] = mye;
      }
      if (b < 31) {  // write prefetched tiles to other buffer
#pragma unroll
        for (int s4 = 0; s4 < 4; ++s4) {
          diagL[nxt][r_ * 65 + c_ + s4 * 4]     = pd[s4].x;
          diagL[nxt][r_ * 65 + c_ + s4 * 4 + 1] = pd[s4].y;
          diagL[nxt][r_ * 65 + c_ + s4 * 4 + 2] = pd[s4].z;
          diagL[nxt][r_ * 65 + c_ + s4 * 4 + 3] = pd[s4].w;
          *(float4*)&chunkL[nxt][r_ * 68 + c_ + s4 * 4] = pc[s4];
        }
      }
      __threadfence();
      __syncthreads();
      if (t == 0)
        __hip_atomic_store(&flags[0], (unsigned)(b + 1), __ATOMIC_RELEASE,
                           __HIP_MEMORY_SCOPE_AGENT);
    }
  } else {
    const int r = g;            // 1..31
    const int lr = t & 63, q = t >> 6;
    const int grow = r * 64 + lr;
    const float* hrow = H22 + (size_t)grow * 2048;
    float part = 0.f;
    for (int j = 0; j < r - 1; ++j) {
      const float* hp = hrow + j * 64 + q * 16;
      const float4 h0 = *(const float4*)(hp);
      const float4 h1 = *(const float4*)(hp + 4);
      const float4 h2 = *(const float4*)(hp + 8);
      const float4 h3 = *(const float4*)(hp + 12);
      while (__hip_atomic_load(&flags[0], __ATOMIC_ACQUIRE,
                               __HIP_MEMORY_SCOPE_AGENT) < (unsigned)(j + 1))
        __builtin_amdgcn_s_sleep(1);
      const float* ep = eps_g + j * 64 + q * 16;
      const float4 e0 = *(const float4*)(ep);
      const float4 e1 = *(const float4*)(ep + 4);
      const float4 e2 = *(const float4*)(ep + 8);
      const float4 e3 = *(const float4*)(ep + 12);
      part -= h0.x * e0.x + h0.y * e0.y + h0.z * e0.z + h0.w * e0.w
            + h1.x * e1.x + h1.y * e1.y + h1.z * e1.z + h1.w * e1.w
            + h2.x * e2.x + h2.y * e2.y + h2.z * e2.z + h2.w * e2.w
            + h3.x * e3.x + h3.y * e3.y + h3.z * e3.z + h3.w * e3.w;
    }
    redL[q * 64 + lr] = part;
    __syncthreads();
    if (t < 64)
      accfin[r * 64 + t] = bacc[r * 64 + t] + redL[t] + redL[64 + t] +
                           redL[128 + t] + redL[192 + t];
    __threadfence();
    __syncthreads();
    if (t == 0)
      __hip_atomic_store(&flags[64 + r * 16], 1u, __ATOMIC_RELEASE,
                         __HIP_MEMORY_SCOPE_AGENT);
  }
}

// ---------- 5) persistent solver: r0 = H31@xi + H32@eps + B2@w; then NCHEB Chebyshev iters ----------
__global__ __launch_bounds__(256) void k_solve(const float* __restrict__ E,
                                               const float* __restrict__ H31,
                                               const float* __restrict__ H32,
                                               const float* __restrict__ B2,
                                               const float* __restrict__ xi,
                                               const float* __restrict__ eps_g,
                                               const float* __restrict__ w,
                                               float* __restrict__ xv,
                                               float* __restrict__ rbuf,
                                               float* __restrict__ dbuf,
                                               unsigned* __restrict__ cnt,
                                               Coefs cf) {
  __shared__ float dn[NXI];
  const int g = blockIdx.x, t = threadIdx.x;
  const int lane = t & 63, wv = t >> 6;
  // stage: r0 for our 16 rows
#pragma unroll
  for (int rr = 0; rr < 4; ++rr) {
    const int row = g * 16 + wv * 4 + rr;
    const float* fr = H31 + (size_t)row * NXI;
    const float* br = H32 + (size_t)row * NXI;
    float s = 0.f;
    for (int k0 = 0; k0 < NXI; k0 += 256) {
      const int li = k0 + lane * 4;
      const float4 a = *(const float4*)(fr + li);
      const float4 x4 = *(const float4*)(xi + li);
      const float4 b = *(const float4*)(br + li);
      const float4 e4 = *(const float4*)(eps_g + li);
      s += a.x * x4.x + a.y * x4.y + a.z * x4.z + a.w * x4.w
         + b.x * e4.x + b.y * e4.y + b.z * e4.z + b.w * e4.w;
    }
    const float* b2r = B2 + (size_t)row * NN;
    for (int k0 = 0; k0 < NN; k0 += 256) {
      const int li = k0 + lane * 4;
      const float4 a = *(const float4*)(b2r + li);
      const float4 w4 = *(const float4*)(w + li);
      s += a.x * w4.x + a.y * w4.y + a.z * w4.z + a.w * w4.w;
    }
#pragma unroll
    for (int off = 32; off > 0; off >>= 1) s += __shfl_xor(s, off, 64);
    if (lane == 0) rbuf[row] = s;
  }
  gridbar(cnt, 128u);
  for (int i = 0; i < NCHEB; ++i) {
    const float* rin = rbuf + (i & 1) * NXI;
    float* rout = rbuf + ((i + 1) & 1) * NXI;
    const float* din = dbuf + (i & 1) * NXI;
    float* dout = dbuf + ((i + 1) & 1) * NXI;
    const float a1 = cf.g1[i], a2 = cf.g2[i];
    for (int j = t; j < NXI; j += 256) dn[j] = a1 * din[j] + a2 * rin[j];
    __syncthreads();
#pragma unroll
    for (int rr = 0; rr < 4; ++rr) {
      const int row = g * 16 + wv * 4 + rr;
      const float* er = E + (size_t)row * NXI;
      float s = 0.f;
      for (int k0 = 0; k0 < NXI; k0 += 256) {
        const int li = k0 + lane * 4;
        const float4 ev = *(const float4*)(er + li);
        s += ev.x * dn[li] + ev.y * dn[li + 1] + ev.z * dn[li + 2] + ev.w * dn[li + 3];
      }
#pragma unroll
      for (int off = 32; off > 0; off >>= 1) s += __shfl_xor(s, off, 64);
      if (lane == 0) {
        xv[row] += dn[row];
        rout[row] = rin[row] - s;
        dout[row] = dn[row];
      }
    }
    gridbar(cnt, (unsigned)((i + 2) * 128));
  }
}

// ---------- 6) outputs ----------
__global__ __launch_bounds__(256) void k_out(const float* __restrict__ C2,
                                             const float* __restrict__ D21,
                                             const float* __restrict__ D22,
                                             const float* __restrict__ xi,
                                             const float* __restrict__ eps_g,
                                             const float* __restrict__ w,
                                             const float* __restrict__ bu,
                                             const float* __restrict__ x,
                                             float* __restrict__ out) {
  const int t = threadIdx.x, g = blockIdx.x;
  const int gid = g * 256 + t;
  if (gid < NXI) out[MM + gid] = x[gid];
  const int lane = t & 63;
  const int wv = g * 4 + (t >> 6);
  for (int row = wv; row < MM; row += 512) {
    const float* c2r = C2 + (size_t)row * NXI;
    const float* d21r = D21 + (size_t)row * LLEN;
    const float* d22r = D22 + (size_t)row * NN;
    float s = 0.f;
    for (int k0 = 0; k0 < NXI; k0 += 256) {
      const int li = k0 + lane * 4;
      const float4 a = *(const float4*)(c2r + li);
      const float4 xvv = *(const float4*)(xi + li);
      const float4 b = *(const float4*)(d21r + li);
      const float4 ev = *(const float4*)(eps_g + li);
      s += a.x * xvv.x + a.y * xvv.y + a.z * xvv.z + a.w * xvv.w
         + b.x * ev.x + b.y * ev.y + b.z * ev.z + b.w * ev.w;
    }
    for (int k0 = 0; k0 < NN; k0 += 256) {
      const int li = k0 + lane * 4;
      const float4 a = *(const float4*)(d22r + li);
      const float4 w4 = *(const float4*)(w + li);
      s += a.x * w4.x + a.y * w4.y + a.z * w4.z + a.w * w4.w;
    }
#pragma unroll
    for (int off = 32; off > 0; off >>= 1) s += __shfl_xor(s, off, 64);
    if (lane == 0) {
      const float u = s + bu[row];
      const float sg = 1.f / (1.f + __expf(-u));
      out[row] = 8.0f + 4.8f * sg;
    }
  }
}

// ---------- launch ----------
extern "C" void kernel_launch(void* const* d_in, const int* in_sizes, int n_in,
                              void* d_out, int out_size, void* d_ws, size_t ws_size,
                              hipStream_t stream) {
  (void)in_sizes; (void)n_in; (void)out_size;
  const float* w   = (const float*)d_in[1];
  const float* xi  = (const float*)d_in[2];
  const float* X   = (const float*)d_in[3];
  const float* Y   = (const float*)d_in[4];
  const float* B2  = (const float*)d_in[5];
  const float* C2  = (const float*)d_in[6];
  const float* D21 = (const float*)d_in[7];
  const float* D22 = (const float*)d_in[8];
  const float* D12 = (const float*)d_in[9];
  const float* bu  = (const float*)d_in[10];
  float* out = (float*)d_out;

  char* ws = (char*)d_ws;
  ushort_t* XT = (ushort_t*)ws;                                   // 75,497,472 B
  float* H = (float*)(ws + 75497472ull);                          // 100,663,296 B
  float* vecs = (float*)(ws + 75497472ull + 100663296ull);
  float* invLam = vecs;              // 2048
  float* bacc   = vecs + 2048;
  float* accfin = vecs + 4096;
  float* eps_g  = vecs + 6144;
  float* xv     = vecs + 8192;
  float* rbuf   = vecs + 10240;      // 2 x 2048
  float* dbuf   = vecs + 14336;      // 2 x 2048
  unsigned* flags = (unsigned*)(vecs + 18432);   // 8 KB zeroed
  unsigned* cnt   = flags + 1024;

  float* H11 = H;                          // becomes E after k_mid
  float* H21 = H + 1ull * 2048 * 2048;
  float* H22 = H + 2ull * 2048 * 2048;
  float* H31 = H + 3ull * 2048 * 2048;
  float* H32 = H + 4ull * 2048 * 2048;
  float* H33 = H + 5ull * 2048 * 2048;

  hipMemsetAsync(flags, 0, 8192, stream);
  hipMemsetAsync(xv, 0, 2048 * sizeof(float), stream);

  k_transpose<<<dim3(96, 96), 256, 0, stream>>>(X, XT);
  k_syrk<<<dim3(8, 8, 6), 512, 0, stream>>>(XT, H);
  k_mid<<<1160, 256, 0, stream>>>(H11, H33, Y, H22, invLam, H21, D12, xi, w, bacc);
  k_eps<<<32, 256, 0, stream>>>(H22, bacc, invLam, eps_g, accfin, flags);

  // Chebyshev coefficients on [16, 130] (Re-spectrum of E ~ [21.5, 121.8])
  Coefs cf;
  {
    const double lmin = 16.0, lmax = 130.0;
    const double theta = 0.5 * (lmax + lmin), delta = 0.5 * (lmax - lmin);
    const double sigma1 = theta / delta;
    double rho_prev = delta / theta;
    for (int i = 0; i < NCHEB; ++i) {
      if (i == 0) { cf.g1[0] = 0.f; cf.g2[0] = (float)(1.0 / theta); }
      else {
        const double rho = 1.0 / (2.0 * sigma1 - rho_prev);
        cf.g1[i] = (float)(rho * rho_prev);
        cf.g2[i] = (float)(2.0 * rho / delta);
        rho_prev = rho;
      }
    }
  }
  k_solve<<<128, 256, 0, stream>>>(H11, H31, H32, B2, xi, eps_g, w,
                                   xv, rbuf, dbuf, cnt, cf);
  k_out<<<128, 256, 0, stream>>>(C2, D21, D22, xi, eps_g, w, bu, xv, out);
}